// Round 14
// baseline (174.235 us; speedup 1.0000x reference)
//
#include <hip/hip_runtime.h>

typedef _Float16 half8  __attribute__((ext_vector_type(8)));
typedef _Float16 half2v __attribute__((ext_vector_type(2)));
typedef short    s16x8  __attribute__((ext_vector_type(8)));
typedef float    f32x4  __attribute__((ext_vector_type(4)));
typedef int      i32x4  __attribute__((ext_vector_type(4)));

#define LL 256
#define DD 64
#define BB 32
#define LREL 0.01f
#define EMBC (LL*DD + 1)       // 16385
#define NTILE 72               // per-batch 16i x 32j upper-tri tiles
#define NBLK_MAIN (BB * NTILE) // 2304

// ---------------- main: fully fused pairwise MLP ----------------
// 128 thr = 2 waves; tile 16i x 32j; wave w owns j-strip [j0+16w, j0+16w+16).
// layer1->layer2 entirely in registers (custom layer2 k-map = producer layout).
// launch_bounds(...,4): keep VGPR <=128 so 4 waves/SIMD are resident (m69 cliff).
__global__ __launch_bounds__(128, 4) void k_main(
    const float* __restrict__ emb, const float* __restrict__ tw,
    const float* __restrict__ w1, const float* __restrict__ b1,
    const float* __restrict__ w2, const float* __restrict__ b2,
    const float* __restrict__ w3, const float* __restrict__ b3,
    float* __restrict__ part)
{
    const int tid = threadIdx.x;
    const int lane = tid & 63, wid = tid >> 6;
    const int g = lane >> 4, p = lane & 15;

    const int blk = blockIdx.x;
    const int batch = blk / NTILE;
    const int t = blk - batch * NTILE;
    int bj, bi;   // cumulative tile counts {2,6,12,20,30,42,56,72}
    if (t < 12)      { if (t < 2) { bj = 0; bi = t; } else if (t < 6) { bj = 1; bi = t - 2; } else { bj = 2; bi = t - 6; } }
    else if (t < 30) { if (t < 20) { bj = 3; bi = t - 12; } else { bj = 4; bi = t - 20; } }
    else             { if (t < 42) { bj = 5; bi = t - 30; } else if (t < 56) { bj = 6; bi = t - 42; } else { bj = 7; bi = t - 56; } }
    const int i0 = bi * 16, j0 = bj * 32;

    __shared__ _Float16 yts[48][72];   // rows 0..15 = i-tile, 16..47 = j-tile (144B rows)
    __shared__ float masks[48];
    __shared__ float wsum[2];

    const float* erow = emb + (size_t)batch * EMBC;

    // stage y = emb*tw as f16, wave-per-row (row = 2k+wid, col = lane);
    // row mask fused via ballot: (sum|e|>0) == any(e != 0).
    for (int k = 0; k < 24; ++k) {
        int row = k * 2 + wid;
        int pos = (row < 16) ? (i0 + row) : (j0 + row - 16);
        float e = erow[pos * 64 + lane];
        float tt = tw[pos * 64 + lane];
        yts[row][lane] = (_Float16)(e * tt);
        int nz = __any(e != 0.f);
        if (lane == 0) masks[row] = nz ? 1.f : 0.f;
    }

    // w1 fragments from f32 (k-map f = kb*32+g*8+e); fold 0.5 into sum-cols (f<64)
    half8 w1f[4][4];
    #pragma unroll
    for (int T = 0; T < 4; ++T) {
        #pragma unroll
        for (int kb = 0; kb < 4; ++kb) {
            const float* src = w1 + (T * 16 + p) * 128 + kb * 32 + g * 8;
            f32x4 lo = *(const f32x4*)src;
            f32x4 hi = *(const f32x4*)(src + 4);
            const float s = (kb < 2) ? 0.5f : 1.0f;
            half8 h;
            #pragma unroll
            for (int e = 0; e < 4; ++e) {
                h[e]     = (_Float16)(lo[e] * s);
                h[e + 4] = (_Float16)(hi[e] * s);
            }
            w1f[T][kb] = h;
        }
    }
    // w2 fragments with the custom layer-2 k-map d=(2kb+(e>>2))*16+g*4+(e&3)
    half8 w2f[2];
    #pragma unroll
    for (int kb = 0; kb < 2; ++kb) {
        const float* r2 = w2 + p * 64;
        f32x4 lo = *(const f32x4*)(r2 + (2 * kb) * 16 + g * 4);
        f32x4 hi = *(const f32x4*)(r2 + (2 * kb + 1) * 16 + g * 4);
        half8 h;
        #pragma unroll
        for (int e = 0; e < 4; ++e) {
            h[e]     = (_Float16)lo[e];
            h[e + 4] = (_Float16)hi[e];
        }
        w2f[kb] = h;
    }

    f32x4 b1v[4];
    #pragma unroll
    for (int T = 0; T < 4; ++T) b1v[T] = *(const f32x4*)(b1 + T * 16 + g * 4);
    const f32x4 b2v = *(const f32x4*)(b2 + g * 4);
    const f32x4 w3v = *(const f32x4*)(w3 + g * 4);
    const float b3v = (g == 0) ? b3[0] : 0.f;

    __syncthreads();

    const int jl = wid * 16 + p;
    const int jglob = j0 + jl;
    const float mj = masks[16 + jl];
    const half8 yjA = *(const half8*)&yts[16 + jl][g * 8];
    const half8 yjB = *(const half8*)&yts[16 + jl][32 + g * 8];

    const int jmaxv = j0 + wid * 16 + 15;
    int nil = jmaxv - i0; if (nil > 16) nil = 16;

    const half2v lrel2 = {(_Float16)LREL, (_Float16)LREL};
    const half2v zero2 = {};

    float sacc = 0.f;
    for (int il = 0; il < nil; ++il) {
        const int i = i0 + il;
        const half8 yiA = *(const half8*)&yts[il][g * 8];
        const half8 yiB = *(const half8*)&yts[il][32 + g * 8];

        half8 f0 = yiA + yjA;                        // 2*mean (w1 sum-cols pre-halved)
        half8 f1 = yiB + yjB;
        s16x8 ad0 = __builtin_bit_cast(s16x8, yiA - yjA) & (short)0x7FFF;
        s16x8 ad1 = __builtin_bit_cast(s16x8, yiB - yjB) & (short)0x7FFF;
        half8 f2 = __builtin_bit_cast(half8, ad0);   // |xi-xj| exact
        half8 f3 = __builtin_bit_cast(half8, ad1);

        f32x4 acc[4] = {b1v[0], b1v[1], b1v[2], b1v[3]};   // bias as C-init
        #pragma unroll
        for (int T = 0; T < 4; ++T) {
            acc[T] = __builtin_amdgcn_mfma_f32_16x16x32_f16(w1f[T][0], f0, acc[T], 0, 0, 0);
            acc[T] = __builtin_amdgcn_mfma_f32_16x16x32_f16(w1f[T][1], f1, acc[T], 0, 0, 0);
            acc[T] = __builtin_amdgcn_mfma_f32_16x16x32_f16(w1f[T][2], f2, acc[T], 0, 0, 0);
            acc[T] = __builtin_amdgcn_mfma_f32_16x16x32_f16(w1f[T][3], f3, acc[T], 0, 0, 0);
        }

        // pack to f16 + leaky; hv[T][q] = rows T*16+g*4+{2q,2q+1}, col p
        unsigned hv[4][2];
        #pragma unroll
        for (int T = 0; T < 4; ++T) {
            half2v a = __builtin_bit_cast(half2v, __builtin_amdgcn_cvt_pkrtz(acc[T][0], acc[T][1]));
            half2v b = __builtin_bit_cast(half2v, __builtin_amdgcn_cvt_pkrtz(acc[T][2], acc[T][3]));
            a = __builtin_elementwise_max(a, zero2) + lrel2 * __builtin_elementwise_min(a, zero2);
            b = __builtin_elementwise_max(b, zero2) + lrel2 * __builtin_elementwise_min(b, zero2);
            hv[T][0] = __builtin_bit_cast(unsigned, a);
            hv[T][1] = __builtin_bit_cast(unsigned, b);
        }

        // layer-2 B-frag = register concat (custom k-map matches producer layout)
        i32x4 R0 = {(int)hv[0][0], (int)hv[0][1], (int)hv[1][0], (int)hv[1][1]};
        i32x4 R1 = {(int)hv[2][0], (int)hv[2][1], (int)hv[3][0], (int)hv[3][1]};
        half8 hB0 = __builtin_bit_cast(half8, R0);
        half8 hB1 = __builtin_bit_cast(half8, R1);

        f32x4 a2 = b2v;                               // bias as C-init
        a2 = __builtin_amdgcn_mfma_f32_16x16x32_f16(w2f[0], hB0, a2, 0, 0, 0);
        a2 = __builtin_amdgcn_mfma_f32_16x16x32_f16(w2f[1], hB1, a2, 0, 0, 0);

        float sp = b3v;
        #pragma unroll
        for (int r = 0; r < 4; ++r) {
            float h = a2[r];
            h = fmaxf(h, 0.f) + LREL * fminf(h, 0.f);
            sp = fmaf(h, w3v[r], sp);
        }
        const float mfac = (jglob > i) ? (masks[il] * mj) : 0.f;
        sacc = fmaf(sp, mfac, sacc);
    }

    #pragma unroll
    for (int m = 32; m; m >>= 1) sacc += __shfl_xor(sacc, m, 64);
    if (lane == 0) wsum[wid] = sacc;
    __syncthreads();
    if (tid == 0) part[blk] = wsum[0] + wsum[1];
}

// ---------------- finalize: x1 = emb@tw + tb, out = x1 + scale * sum(part) ----------------
__global__ void k_fin(const float* __restrict__ emb, const float* __restrict__ tw,
                      const float* __restrict__ tb, const float* __restrict__ scale,
                      const float* __restrict__ part, float* __restrict__ out)
{
    const int b = blockIdx.x, tid = threadIdx.x;
    const float* row = emb + (size_t)b * EMBC;
    float s = 0.f;
    for (int c = tid; c < EMBC; c += 256) s = fmaf(row[c], tw[c], s);
    if (tid < NTILE) s += scale[0] * part[b * NTILE + tid];
    __shared__ float red[256];
    red[tid] = s; __syncthreads();
    for (int st = 128; st; st >>= 1) { if (tid < st) red[tid] += red[tid + st]; __syncthreads(); }
    if (tid == 0) out[b] = red[0] + tb[0];
}

extern "C" void kernel_launch(void* const* d_in, const int* in_sizes, int n_in,
                              void* d_out, int out_size, void* d_ws, size_t ws_size,
                              hipStream_t stream)
{
    const float* emb   = (const float*)d_in[0];
    const float* tw    = (const float*)d_in[1];
    const float* tb    = (const float*)d_in[2];
    const float* w1    = (const float*)d_in[3];
    const float* b1    = (const float*)d_in[4];
    const float* w2    = (const float*)d_in[5];
    const float* b2    = (const float*)d_in[6];
    const float* w3    = (const float*)d_in[7];
    const float* b3    = (const float*)d_in[8];
    const float* scale = (const float*)d_in[9];

    float* part = (float*)d_ws;          // NBLK_MAIN floats, written before read, no init needed
    float* out  = (float*)d_out;

    hipLaunchKernelGGL(k_main, dim3(NBLK_MAIN), dim3(128), 0, stream,
                       emb, tw, w1, b1, w2, b2, w3, b3, part);
    hipLaunchKernelGGL(k_fin, dim3(BB), dim3(256), 0, stream,
                       emb, tw, tb, scale, part, out);
}

// Round 17
// 145.498 us; speedup vs baseline: 1.1975x; 1.1975x over previous
//
#include <hip/hip_runtime.h>

typedef _Float16 half8  __attribute__((ext_vector_type(8)));
typedef _Float16 half2v __attribute__((ext_vector_type(2)));
typedef short    s16x8  __attribute__((ext_vector_type(8)));
typedef float    f32x4  __attribute__((ext_vector_type(4)));
typedef int      i32x4  __attribute__((ext_vector_type(4)));

#define LL 256
#define DD 64
#define BB 32
#define LREL 0.01f
#define EMBC (LL*DD + 1)       // 16385
#define NTILE 72               // per-batch 16i x 32j upper-tri tiles
#define NBLK_MAIN (BB * NTILE) // 2304

// ---------------- main: fully fused pairwise MLP, 2-way il ILP ----------------
// 128 thr = 2 waves; tile 16i x 32j; wave w owns j-strip [j0+16w, j0+16w+16).
// layer1->layer2 entirely in registers (custom layer2 k-map = producer layout).
// VGPR target: 129-256 bucket (2 waves/SIMD) — spend headroom on 2-way ILP.
__global__ __launch_bounds__(128) void k_main(
    const float* __restrict__ emb, const float* __restrict__ tw,
    const float* __restrict__ w1, const float* __restrict__ b1,
    const float* __restrict__ w2, const float* __restrict__ b2,
    const float* __restrict__ w3, const float* __restrict__ b3,
    float* __restrict__ part)
{
    const int tid = threadIdx.x;
    const int lane = tid & 63, wid = tid >> 6;
    const int g = lane >> 4, p = lane & 15;

    const int blk = blockIdx.x;
    const int batch = blk / NTILE;
    const int t = blk - batch * NTILE;
    int bj, bi;   // cumulative tile counts {2,6,12,20,30,42,56,72}
    if (t < 12)      { if (t < 2) { bj = 0; bi = t; } else if (t < 6) { bj = 1; bi = t - 2; } else { bj = 2; bi = t - 6; } }
    else if (t < 30) { if (t < 20) { bj = 3; bi = t - 12; } else { bj = 4; bi = t - 20; } }
    else             { if (t < 42) { bj = 5; bi = t - 30; } else if (t < 56) { bj = 6; bi = t - 42; } else { bj = 7; bi = t - 56; } }
    const int i0 = bi * 16, j0 = bj * 32;

    __shared__ _Float16 yts[48][72];   // rows 0..15 = i-tile, 16..47 = j-tile (144B rows)
    __shared__ float masks[48];
    __shared__ float wsum[2];

    const float* erow = emb + (size_t)batch * EMBC;

    // stage y = emb*tw as f16, wave-per-row; row mask fused via ballot
    for (int k = 0; k < 24; ++k) {
        int row = k * 2 + wid;
        int pos = (row < 16) ? (i0 + row) : (j0 + row - 16);
        float e = erow[pos * 64 + lane];
        float tt = tw[pos * 64 + lane];
        yts[row][lane] = (_Float16)(e * tt);
        int nz = __any(e != 0.f);
        if (lane == 0) masks[row] = nz ? 1.f : 0.f;
    }

    // w1 fragments from f32 (k-map f = kb*32+g*8+e); fold 0.5 into sum-cols (f<64)
    half8 w1f[4][4];
    #pragma unroll
    for (int T = 0; T < 4; ++T) {
        #pragma unroll
        for (int kb = 0; kb < 4; ++kb) {
            const float* src = w1 + (T * 16 + p) * 128 + kb * 32 + g * 8;
            f32x4 lo = *(const f32x4*)src;
            f32x4 hi = *(const f32x4*)(src + 4);
            const float s = (kb < 2) ? 0.5f : 1.0f;
            half8 h;
            #pragma unroll
            for (int e = 0; e < 4; ++e) {
                h[e]     = (_Float16)(lo[e] * s);
                h[e + 4] = (_Float16)(hi[e] * s);
            }
            w1f[T][kb] = h;
        }
    }
    // w2 fragments with the custom layer-2 k-map d=(2kb+(e>>2))*16+g*4+(e&3)
    half8 w2f[2];
    #pragma unroll
    for (int kb = 0; kb < 2; ++kb) {
        const float* r2 = w2 + p * 64;
        f32x4 lo = *(const f32x4*)(r2 + (2 * kb) * 16 + g * 4);
        f32x4 hi = *(const f32x4*)(r2 + (2 * kb + 1) * 16 + g * 4);
        half8 h;
        #pragma unroll
        for (int e = 0; e < 4; ++e) {
            h[e]     = (_Float16)lo[e];
            h[e + 4] = (_Float16)hi[e];
        }
        w2f[kb] = h;
    }

    f32x4 b1v[4];
    #pragma unroll
    for (int T = 0; T < 4; ++T) b1v[T] = *(const f32x4*)(b1 + T * 16 + g * 4);
    const f32x4 b2v = *(const f32x4*)(b2 + g * 4);
    const f32x4 w3v = *(const f32x4*)(w3 + g * 4);
    const float b3v = (g == 0) ? b3[0] : 0.f;

    __syncthreads();

    const int jl = wid * 16 + p;
    const int jglob = j0 + jl;
    const float mj = masks[16 + jl];
    const half8 yjA = *(const half8*)&yts[16 + jl][g * 8];
    const half8 yjB = *(const half8*)&yts[16 + jl][32 + g * 8];

    const int jmaxv = j0 + wid * 16 + 15;
    int ilmax = jmaxv - i0; if (ilmax > 16) ilmax = 16;
    const int il2 = (ilmax + 1) & ~1;     // round up even; mfac masks the phantom slot

    const half2v lrel2 = {(_Float16)LREL, (_Float16)LREL};
    const half2v zero2 = {};

    float sacc = 0.f;
    for (int il = 0; il < il2; il += 2) {
        // ---- slot A: row il; slot B: row il+1 (independent chains) ----
        const half8 yiA0 = *(const half8*)&yts[il][g * 8];
        const half8 yiB0 = *(const half8*)&yts[il][32 + g * 8];
        const half8 yiA1 = *(const half8*)&yts[il + 1][g * 8];
        const half8 yiB1 = *(const half8*)&yts[il + 1][32 + g * 8];

        half8 f0a = yiA0 + yjA, f1a = yiB0 + yjB;
        half8 f0b = yiA1 + yjA, f1b = yiB1 + yjB;
        s16x8 ad0a = __builtin_bit_cast(s16x8, yiA0 - yjA) & (short)0x7FFF;
        s16x8 ad1a = __builtin_bit_cast(s16x8, yiB0 - yjB) & (short)0x7FFF;
        s16x8 ad0b = __builtin_bit_cast(s16x8, yiA1 - yjA) & (short)0x7FFF;
        s16x8 ad1b = __builtin_bit_cast(s16x8, yiB1 - yjB) & (short)0x7FFF;
        half8 f2a = __builtin_bit_cast(half8, ad0a), f3a = __builtin_bit_cast(half8, ad1a);
        half8 f2b = __builtin_bit_cast(half8, ad0b), f3b = __builtin_bit_cast(half8, ad1b);

        f32x4 accA[4] = {b1v[0], b1v[1], b1v[2], b1v[3]};
        f32x4 accB[4] = {b1v[0], b1v[1], b1v[2], b1v[3]};
        #pragma unroll
        for (int T = 0; T < 4; ++T) {
            accA[T] = __builtin_amdgcn_mfma_f32_16x16x32_f16(w1f[T][0], f0a, accA[T], 0, 0, 0);
            accB[T] = __builtin_amdgcn_mfma_f32_16x16x32_f16(w1f[T][0], f0b, accB[T], 0, 0, 0);
            accA[T] = __builtin_amdgcn_mfma_f32_16x16x32_f16(w1f[T][1], f1a, accA[T], 0, 0, 0);
            accB[T] = __builtin_amdgcn_mfma_f32_16x16x32_f16(w1f[T][1], f1b, accB[T], 0, 0, 0);
            accA[T] = __builtin_amdgcn_mfma_f32_16x16x32_f16(w1f[T][2], f2a, accA[T], 0, 0, 0);
            accB[T] = __builtin_amdgcn_mfma_f32_16x16x32_f16(w1f[T][2], f2b, accB[T], 0, 0, 0);
            accA[T] = __builtin_amdgcn_mfma_f32_16x16x32_f16(w1f[T][3], f3a, accA[T], 0, 0, 0);
            accB[T] = __builtin_amdgcn_mfma_f32_16x16x32_f16(w1f[T][3], f3b, accB[T], 0, 0, 0);
        }

        unsigned hvA[4][2], hvB[4][2];
        #pragma unroll
        for (int T = 0; T < 4; ++T) {
            half2v a0 = __builtin_bit_cast(half2v, __builtin_amdgcn_cvt_pkrtz(accA[T][0], accA[T][1]));
            half2v a1 = __builtin_bit_cast(half2v, __builtin_amdgcn_cvt_pkrtz(accA[T][2], accA[T][3]));
            half2v b0 = __builtin_bit_cast(half2v, __builtin_amdgcn_cvt_pkrtz(accB[T][0], accB[T][1]));
            half2v b1h = __builtin_bit_cast(half2v, __builtin_amdgcn_cvt_pkrtz(accB[T][2], accB[T][3]));
            a0 = __builtin_elementwise_max(a0, zero2) + lrel2 * __builtin_elementwise_min(a0, zero2);
            a1 = __builtin_elementwise_max(a1, zero2) + lrel2 * __builtin_elementwise_min(a1, zero2);
            b0 = __builtin_elementwise_max(b0, zero2) + lrel2 * __builtin_elementwise_min(b0, zero2);
            b1h = __builtin_elementwise_max(b1h, zero2) + lrel2 * __builtin_elementwise_min(b1h, zero2);
            hvA[T][0] = __builtin_bit_cast(unsigned, a0);
            hvA[T][1] = __builtin_bit_cast(unsigned, a1);
            hvB[T][0] = __builtin_bit_cast(unsigned, b0);
            hvB[T][1] = __builtin_bit_cast(unsigned, b1h);
        }

        i32x4 RA0 = {(int)hvA[0][0], (int)hvA[0][1], (int)hvA[1][0], (int)hvA[1][1]};
        i32x4 RA1 = {(int)hvA[2][0], (int)hvA[2][1], (int)hvA[3][0], (int)hvA[3][1]};
        i32x4 RB0 = {(int)hvB[0][0], (int)hvB[0][1], (int)hvB[1][0], (int)hvB[1][1]};
        i32x4 RB1 = {(int)hvB[2][0], (int)hvB[2][1], (int)hvB[3][0], (int)hvB[3][1]};

        f32x4 a2A = b2v, a2B = b2v;
        a2A = __builtin_amdgcn_mfma_f32_16x16x32_f16(w2f[0], __builtin_bit_cast(half8, RA0), a2A, 0, 0, 0);
        a2B = __builtin_amdgcn_mfma_f32_16x16x32_f16(w2f[0], __builtin_bit_cast(half8, RB0), a2B, 0, 0, 0);
        a2A = __builtin_amdgcn_mfma_f32_16x16x32_f16(w2f[1], __builtin_bit_cast(half8, RA1), a2A, 0, 0, 0);
        a2B = __builtin_amdgcn_mfma_f32_16x16x32_f16(w2f[1], __builtin_bit_cast(half8, RB1), a2B, 0, 0, 0);

        float spA = b3v, spB = b3v;
        #pragma unroll
        for (int r = 0; r < 4; ++r) {
            float hA = a2A[r], hB = a2B[r];
            hA = fmaxf(hA, 0.f) + LREL * fminf(hA, 0.f);
            hB = fmaxf(hB, 0.f) + LREL * fminf(hB, 0.f);
            spA = fmaf(hA, w3v[r], spA);
            spB = fmaf(hB, w3v[r], spB);
        }
        const int iA = i0 + il, iB = i0 + il + 1;
        const float mfA = (jglob > iA) ? (masks[il] * mj) : 0.f;
        const float mfB = (jglob > iB) ? (masks[il + 1] * mj) : 0.f;
        sacc = fmaf(spA, mfA, sacc);
        sacc = fmaf(spB, mfB, sacc);
    }

    #pragma unroll
    for (int m = 32; m; m >>= 1) sacc += __shfl_xor(sacc, m, 64);
    if (lane == 0) wsum[wid] = sacc;
    __syncthreads();
    if (tid == 0) part[blk] = wsum[0] + wsum[1];
}

// ---------------- finalize: x1 = emb@tw + tb, out = x1 + scale * sum(part) ----------------
__global__ void k_fin(const float* __restrict__ emb, const float* __restrict__ tw,
                      const float* __restrict__ tb, const float* __restrict__ scale,
                      const float* __restrict__ part, float* __restrict__ out)
{
    const int b = blockIdx.x, tid = threadIdx.x;
    const float* row = emb + (size_t)b * EMBC;
    float s = 0.f;
    for (int c = tid; c < EMBC; c += 256) s = fmaf(row[c], tw[c], s);
    if (tid < NTILE) s += scale[0] * part[b * NTILE + tid];
    __shared__ float red[256];
    red[tid] = s; __syncthreads();
    for (int st = 128; st; st >>= 1) { if (tid < st) red[tid] += red[tid + st]; __syncthreads(); }
    if (tid == 0) out[b] = red[0] + tb[0];
}

extern "C" void kernel_launch(void* const* d_in, const int* in_sizes, int n_in,
                              void* d_out, int out_size, void* d_ws, size_t ws_size,
                              hipStream_t stream)
{
    const float* emb   = (const float*)d_in[0];
    const float* tw    = (const float*)d_in[1];
    const float* tb    = (const float*)d_in[2];
    const float* w1    = (const float*)d_in[3];
    const float* b1    = (const float*)d_in[4];
    const float* w2    = (const float*)d_in[5];
    const float* b2    = (const float*)d_in[6];
    const float* w3    = (const float*)d_in[7];
    const float* b3    = (const float*)d_in[8];
    const float* scale = (const float*)d_in[9];

    float* part = (float*)d_ws;          // NBLK_MAIN floats, written before read, no init needed
    float* out  = (float*)d_out;

    hipLaunchKernelGGL(k_main, dim3(NBLK_MAIN), dim3(128), 0, stream,
                       emb, tw, w1, b1, w2, b2, w3, b3, part);
    hipLaunchKernelGGL(k_fin, dim3(BB), dim3(256), 0, stream,
                       emb, tw, tb, scale, part, out);
}